// Round 1
// baseline (1462.227 us; speedup 1.0000x reference)
//
#include <hip/hip_runtime.h>
#include <math.h>

#define WS 7
#define N 49         // tokens per window
#define C 96         // dim
#define C3 288       // 3*dim
#define HEADS 3
#define HD 32        // head dim
#define NREL 169     // (2*7-1)^2

// One block per window. blk = b*64 + hh*8 + ww.
// Window (hh,ww) token (p,q) <-> pixel (p*8+hh, q*8+ww)  [strided Swin split]
__global__ void winattn_fp32(const float* __restrict__ x,
                             const float* __restrict__ w_qkv,
                             const float* __restrict__ b_qkv,
                             const float* __restrict__ rel_pos,
                             const float* __restrict__ w_out,
                             const float* __restrict__ b_out,
                             float* __restrict__ out) {
    __shared__ float s_x[N][C];        // 18816 B; reused for attention output
    __shared__ float s_qkv[N][C3];     // 56448 B
    __shared__ float s_rel[HEADS * NREL];

    const int t  = threadIdx.x;
    const int blk = blockIdx.x;
    const int ww = blk & 7;
    const int hh = (blk >> 3) & 7;
    const int b  = blk >> 6;

    for (int i = t; i < HEADS * NREL; i += 256) s_rel[i] = rel_pos[i];

    // ---- load window input (float4, coalesced per token row) ----
    const float* xb = x + (size_t)b * 56 * 56 * C;
    for (int i = t; i < N * C / 4; i += 256) {    // 1176 float4s
        int tok = i / 24;
        int ch4 = i % 24;
        int p = tok / 7, q = tok % 7;
        float4 v = *(const float4*)(xb + (((p * 8 + hh) * 56) + (q * 8 + ww)) * C + ch4 * 4);
        *(float4*)(&s_x[tok][ch4 * 4]) = v;
    }
    __syncthreads();

    // ---- QKV projection: (49 x 96) @ (96 x 288) + bias ----
    // unit = 7-row group x 4-col group; 72 col-groups * 7 row-groups = 504 units
    for (int u = t; u < 504; u += 256) {
        int cg = u % 72, rg = u / 72;
        int col = cg * 4;
        int r0 = rg * 7;
        float4 bq = *(const float4*)(b_qkv + col);
        float acc[7][4];
#pragma unroll
        for (int r = 0; r < 7; ++r) {
            acc[r][0] = bq.x; acc[r][1] = bq.y; acc[r][2] = bq.z; acc[r][3] = bq.w;
        }
        for (int k = 0; k < C; k += 4) {
            float4 w0 = *(const float4*)(w_qkv + (size_t)(k + 0) * C3 + col);
            float4 w1 = *(const float4*)(w_qkv + (size_t)(k + 1) * C3 + col);
            float4 w2 = *(const float4*)(w_qkv + (size_t)(k + 2) * C3 + col);
            float4 w3 = *(const float4*)(w_qkv + (size_t)(k + 3) * C3 + col);
#pragma unroll
            for (int r = 0; r < 7; ++r) {
                float4 xv = *(const float4*)(&s_x[r0 + r][k]);
                acc[r][0] += xv.x * w0.x + xv.y * w1.x + xv.z * w2.x + xv.w * w3.x;
                acc[r][1] += xv.x * w0.y + xv.y * w1.y + xv.z * w2.y + xv.w * w3.y;
                acc[r][2] += xv.x * w0.z + xv.y * w1.z + xv.z * w2.z + xv.w * w3.z;
                acc[r][3] += xv.x * w0.w + xv.y * w1.w + xv.z * w2.w + xv.w * w3.w;
            }
        }
#pragma unroll
        for (int r = 0; r < 7; ++r)
            *(float4*)(&s_qkv[r0 + r][col]) =
                make_float4(acc[r][0], acc[r][1], acc[r][2], acc[r][3]);
    }
    __syncthreads();

    // ---- attention: one thread per (head g, query row qi), 147 threads ----
    if (t < HEADS * N) {
        const int g = t / N, qi = t - g * N;
        const int pi = qi / 7, qq = qi - pi * 7;
        const float scale = 0.17677669529663687f;   // 32^-0.5
        float qreg[HD];
#pragma unroll
        for (int d = 0; d < HD; d += 4) {
            float4 v = *(const float4*)(&s_qkv[qi][g * HD + d]);
            qreg[d] = v.x * scale; qreg[d + 1] = v.y * scale;
            qreg[d + 2] = v.z * scale; qreg[d + 3] = v.w * scale;
        }
        const float* relg = &s_rel[g * NREL];
        float sim[N];
        float m = -1e30f;
        int pj = 0, qj = 0;
        for (int j = 0; j < N; ++j) {
            float a = 0.f;
            const float* kr = &s_qkv[j][C + g * HD];
#pragma unroll
            for (int d = 0; d < HD; d += 4) {
                float4 kv = *(const float4*)(kr + d);
                a += qreg[d] * kv.x + qreg[d + 1] * kv.y +
                     qreg[d + 2] * kv.z + qreg[d + 3] * kv.w;
            }
            a += relg[(pi - pj + 6) * 13 + (qq - qj + 6)];
            sim[j] = a;
            m = fmaxf(m, a);
            if (++qj == 7) { qj = 0; ++pj; }
        }
        float s = 0.f;
        for (int j = 0; j < N; ++j) { float e = __expf(sim[j] - m); sim[j] = e; s += e; }
        float inv = 1.f / s;
        float o[HD];
#pragma unroll
        for (int d = 0; d < HD; ++d) o[d] = 0.f;
        for (int j = 0; j < N; ++j) {
            float p = sim[j];
            const float* vr = &s_qkv[j][2 * C + g * HD];
#pragma unroll
            for (int d = 0; d < HD; d += 4) {
                float4 vv = *(const float4*)(vr + d);
                o[d] += p * vv.x; o[d + 1] += p * vv.y;
                o[d + 2] += p * vv.z; o[d + 3] += p * vv.w;
            }
        }
        // s_x readers all completed before the previous barrier -> safe to reuse
#pragma unroll
        for (int d = 0; d < HD; d += 4) {
            *(float4*)(&s_x[qi][g * HD + d]) =
                make_float4(o[d] * inv, o[d + 1] * inv, o[d + 2] * inv, o[d + 3] * inv);
        }
    }
    __syncthreads();

    // ---- output projection: (49 x 96) @ (96 x 96) + bias, scatter to pixels ----
    // unit = 7-row group x 2-col group; 48 * 7 = 336 units
    for (int u = t; u < 336; u += 256) {
        int cg = u % 48, rg = u / 48;
        int col = cg * 2;
        int r0 = rg * 7;
        float b0 = b_out[col], b1 = b_out[col + 1];
        float acc[7][2];
#pragma unroll
        for (int r = 0; r < 7; ++r) { acc[r][0] = b0; acc[r][1] = b1; }
        for (int k = 0; k < C; k += 4) {
            float2 w0 = *(const float2*)(w_out + (size_t)(k + 0) * C + col);
            float2 w1 = *(const float2*)(w_out + (size_t)(k + 1) * C + col);
            float2 w2 = *(const float2*)(w_out + (size_t)(k + 2) * C + col);
            float2 w3 = *(const float2*)(w_out + (size_t)(k + 3) * C + col);
#pragma unroll
            for (int r = 0; r < 7; ++r) {
                float4 xv = *(const float4*)(&s_x[r0 + r][k]);
                acc[r][0] += xv.x * w0.x + xv.y * w1.x + xv.z * w2.x + xv.w * w3.x;
                acc[r][1] += xv.x * w0.y + xv.y * w1.y + xv.z * w2.y + xv.w * w3.y;
            }
        }
        // rows r0..r0+6 are tokens (p=rg, q=r) -> pixel (rg*8+hh, r*8+ww)
#pragma unroll
        for (int r = 0; r < 7; ++r) {
            *(float2*)(out + (size_t)(((b * 56 + rg * 8 + hh) * 56) + r * 8 + ww) * C + col) =
                make_float2(acc[r][0], acc[r][1]);
        }
    }
}

extern "C" void kernel_launch(void* const* d_in, const int* in_sizes, int n_in,
                              void* d_out, int out_size, void* d_ws, size_t ws_size,
                              hipStream_t stream) {
    const float* x       = (const float*)d_in[0];
    const float* w_qkv   = (const float*)d_in[1];
    const float* b_qkv   = (const float*)d_in[2];
    const float* rel_pos = (const float*)d_in[3];
    const float* w_out   = (const float*)d_in[4];
    const float* b_out   = (const float*)d_in[5];
    float* out = (float*)d_out;

    hipLaunchKernelGGL(winattn_fp32, dim3(64 * 8 * 8), dim3(256), 0, stream,
                       x, w_qkv, b_qkv, rel_pos, w_out, b_out, out);
}

// Round 2
// 583.140 us; speedup vs baseline: 2.5075x; 2.5075x over previous
//
#include <hip/hip_runtime.h>
#include <math.h>

#define SCALE 0.17677669529663687f   // 32^-0.5

typedef float f32x4 __attribute__((ext_vector_type(4)));
typedef short s16x8 __attribute__((ext_vector_type(8)));

__device__ __forceinline__ unsigned short f2bf(float f) {
    unsigned int u = __float_as_uint(f);
    u += 0x7fffu + ((u >> 16) & 1u);          // RNE
    return (unsigned short)(u >> 16);
}
__device__ __forceinline__ float bf_lo(unsigned int u) {  // element 0 (low half)
    return __uint_as_float(u << 16);
}
__device__ __forceinline__ float bf_hi(unsigned int u) {  // element 1 (high half)
    return __uint_as_float(u & 0xffff0000u);
}

// ---------------------------------------------------------------------------
// K1: QKV projection GEMM. M=200704 (all pixels), K=96, N=288, bf16 MFMA.
// Wave = 32 rows x 96 cols (2 m-tiles x 6 n-tiles, 3 k-steps of 32).
// q block (cols 0..95) gets (acc+bias)*SCALE; k,v get acc+bias. bf16 out.
// ---------------------------------------------------------------------------
__global__ __launch_bounds__(256, 2) void k_qkv(
        const float* __restrict__ x, const float* __restrict__ w_qkv,
        const float* __restrict__ b_qkv, unsigned short* __restrict__ qkv) {
    const int lane = threadIdx.x & 63;
    const int wid  = blockIdx.x * 4 + (threadIdx.x >> 6);
    const int m2 = wid / 3;                  // 0..6271 (32-row group)
    const int ng = wid - m2 * 3;             // 0..2 (96-col group)
    const int ln = lane & 15;
    const int kg = lane >> 4;
    const int n0 = ng * 96;
    const long r0 = (long)m2 * 32;

    // B fragments (w_qkv columns) -> registers, fp32->bf16
    s16x8 bfrag[6][3];
    float bias[6];
#pragma unroll
    for (int nt = 0; nt < 6; ++nt) {
        const int col = n0 + nt * 16 + ln;
        bias[nt] = b_qkv[col];
#pragma unroll
        for (int ks = 0; ks < 3; ++ks) {
            s16x8 f;
#pragma unroll
            for (int j = 0; j < 8; ++j)
                f[j] = (short)f2bf(w_qkv[(ks * 32 + kg * 8 + j) * 288 + col]);
            bfrag[nt][ks] = f;
        }
    }
    // A fragments (x rows) -> registers, fp32->bf16
    s16x8 afrag[2][3];
#pragma unroll
    for (int mt = 0; mt < 2; ++mt) {
        const long m = r0 + mt * 16 + ln;
#pragma unroll
        for (int ks = 0; ks < 3; ++ks) {
            const float4 a0 = *(const float4*)(x + m * 96 + ks * 32 + kg * 8);
            const float4 a1 = *(const float4*)(x + m * 96 + ks * 32 + kg * 8 + 4);
            s16x8 f;
            f[0] = (short)f2bf(a0.x); f[1] = (short)f2bf(a0.y);
            f[2] = (short)f2bf(a0.z); f[3] = (short)f2bf(a0.w);
            f[4] = (short)f2bf(a1.x); f[5] = (short)f2bf(a1.y);
            f[6] = (short)f2bf(a1.z); f[7] = (short)f2bf(a1.w);
            afrag[mt][ks] = f;
        }
    }

    f32x4 acc[2][6];
#pragma unroll
    for (int mt = 0; mt < 2; ++mt)
#pragma unroll
        for (int nt = 0; nt < 6; ++nt) {
            f32x4 a = {0.f, 0.f, 0.f, 0.f};
#pragma unroll
            for (int ks = 0; ks < 3; ++ks)
                a = __builtin_amdgcn_mfma_f32_16x16x32_bf16(
                        afrag[mt][ks], bfrag[nt][ks], a, 0, 0, 0);
            acc[mt][nt] = a;
        }

    // epilogue: bias (+ SCALE for q cols, i.e. ng==0), bf16 store
    // C/D layout (verified): col = lane&15, row = (lane>>4)*4 + reg
#pragma unroll
    for (int mt = 0; mt < 2; ++mt)
#pragma unroll
        for (int nt = 0; nt < 6; ++nt) {
            const int col = n0 + nt * 16 + ln;
            const long rowb = r0 + mt * 16 + kg * 4;
#pragma unroll
            for (int r = 0; r < 4; ++r) {
                float v = acc[mt][nt][r] + bias[nt];
                if (ng == 0) v *= SCALE;
                qkv[(rowb + r) * 288 + col] = f2bf(v);
            }
        }
}

// ---------------------------------------------------------------------------
// K2: per-window attention, fp32 VALU on bf16 LDS tiles. One block per window.
// qkv row = [q*SCALE+b | k+b | v+b] bf16. Writes attn-out bf16 to ao.
// ---------------------------------------------------------------------------
__global__ __launch_bounds__(256, 2) void k_attn(
        const unsigned short* __restrict__ qkv,
        const float* __restrict__ rel_pos,
        unsigned short* __restrict__ ao) {
    __shared__ unsigned short s_qkv[49 * 288];   // 28224 B
    __shared__ float s_rel[3 * 169];

    const int t = threadIdx.x;
    const int blk = blockIdx.x;
    const int ww = blk & 7, hh = (blk >> 3) & 7, b = blk >> 6;

    for (int i = t; i < 3 * 169; i += 256) s_rel[i] = rel_pos[i];
    for (int idx = t; idx < 49 * 36; idx += 256) {
        const int tok = idx / 36, c = idx - tok * 36;
        const int p = tok / 7, q = tok - p * 7;
        const size_t pixel = (size_t)b * 3136 + (p * 8 + hh) * 56 + q * 8 + ww;
        ((uint4*)s_qkv)[tok * 36 + c] = ((const uint4*)(qkv + pixel * 288))[c];
    }
    __syncthreads();

    if (t < 147) {
        const int g = t / 49, qi = t - g * 49;
        const int pi = qi / 7, qq = qi - pi * 7;

        float qr[32];
        const uint4* qp = (const uint4*)(s_qkv + qi * 288 + g * 32);
#pragma unroll
        for (int c = 0; c < 4; ++c) {
            const uint4 u = qp[c];
            qr[c*8+0] = bf_lo(u.x); qr[c*8+1] = bf_hi(u.x);
            qr[c*8+2] = bf_lo(u.y); qr[c*8+3] = bf_hi(u.y);
            qr[c*8+4] = bf_lo(u.z); qr[c*8+5] = bf_hi(u.z);
            qr[c*8+6] = bf_lo(u.w); qr[c*8+7] = bf_hi(u.w);
        }
        float sim[49];
        float mx = -1e30f;
#pragma unroll
        for (int j = 0; j < 49; ++j) {
            const uint4* kp = (const uint4*)(s_qkv + j * 288 + 96 + g * 32);
            float a = 0.f;
#pragma unroll
            for (int c = 0; c < 4; ++c) {
                const uint4 u = kp[c];
                a += qr[c*8+0]*bf_lo(u.x) + qr[c*8+1]*bf_hi(u.x)
                   + qr[c*8+2]*bf_lo(u.y) + qr[c*8+3]*bf_hi(u.y)
                   + qr[c*8+4]*bf_lo(u.z) + qr[c*8+5]*bf_hi(u.z)
                   + qr[c*8+6]*bf_lo(u.w) + qr[c*8+7]*bf_hi(u.w);
            }
            const int pj = j / 7, qj = j - pj * 7;
            a += s_rel[g * 169 + (pi - pj + 6) * 13 + (qq - qj + 6)];
            sim[j] = a;
            mx = fmaxf(mx, a);
        }
        float s = 0.f;
#pragma unroll
        for (int j = 0; j < 49; ++j) { float e = __expf(sim[j] - mx); sim[j] = e; s += e; }
        const float inv = 1.f / s;

        float o[32];
#pragma unroll
        for (int d = 0; d < 32; ++d) o[d] = 0.f;
#pragma unroll
        for (int j = 0; j < 49; ++j) {
            const uint4* vp = (const uint4*)(s_qkv + j * 288 + 192 + g * 32);
            const float p = sim[j];
#pragma unroll
            for (int c = 0; c < 4; ++c) {
                const uint4 u = vp[c];
                o[c*8+0] += p * bf_lo(u.x); o[c*8+1] += p * bf_hi(u.x);
                o[c*8+2] += p * bf_lo(u.y); o[c*8+3] += p * bf_hi(u.y);
                o[c*8+4] += p * bf_lo(u.z); o[c*8+5] += p * bf_hi(u.z);
                o[c*8+6] += p * bf_lo(u.w); o[c*8+7] += p * bf_hi(u.w);
            }
        }
        const size_t pixel = (size_t)b * 3136 + (pi * 8 + hh) * 56 + qq * 8 + ww;
        uint4* dst = (uint4*)(ao + pixel * 96 + g * 32);
#pragma unroll
        for (int c = 0; c < 4; ++c) {
            uint4 u;
            u.x = (unsigned int)f2bf(o[c*8+0]*inv) | ((unsigned int)f2bf(o[c*8+1]*inv) << 16);
            u.y = (unsigned int)f2bf(o[c*8+2]*inv) | ((unsigned int)f2bf(o[c*8+3]*inv) << 16);
            u.z = (unsigned int)f2bf(o[c*8+4]*inv) | ((unsigned int)f2bf(o[c*8+5]*inv) << 16);
            u.w = (unsigned int)f2bf(o[c*8+6]*inv) | ((unsigned int)f2bf(o[c*8+7]*inv) << 16);
            dst[c] = u;
        }
    }
}

// ---------------------------------------------------------------------------
// K3: output projection GEMM. M=200704, K=96, N=96, A=bf16 (raw), fp32 out.
// Wave = 32 rows x 96 cols.
// ---------------------------------------------------------------------------
__global__ __launch_bounds__(256, 2) void k_oproj(
        const unsigned short* __restrict__ ao, const float* __restrict__ w_out,
        const float* __restrict__ b_out, float* __restrict__ out) {
    const int lane = threadIdx.x & 63;
    const int m2 = blockIdx.x * 4 + (threadIdx.x >> 6);   // 0..6271
    const int ln = lane & 15;
    const int kg = lane >> 4;
    const long r0 = (long)m2 * 32;

    s16x8 bfrag[6][3];
    float bias[6];
#pragma unroll
    for (int nt = 0; nt < 6; ++nt) {
        const int col = nt * 16 + ln;
        bias[nt] = b_out[col];
#pragma unroll
        for (int ks = 0; ks < 3; ++ks) {
            s16x8 f;
#pragma unroll
            for (int j = 0; j < 8; ++j)
                f[j] = (short)f2bf(w_out[(ks * 32 + kg * 8 + j) * 96 + col]);
            bfrag[nt][ks] = f;
        }
    }
    s16x8 afrag[2][3];
#pragma unroll
    for (int mt = 0; mt < 2; ++mt) {
        const long m = r0 + mt * 16 + ln;
#pragma unroll
        for (int ks = 0; ks < 3; ++ks)
            afrag[mt][ks] = *(const s16x8*)(ao + m * 96 + ks * 32 + kg * 8);
    }

    f32x4 acc[2][6];
#pragma unroll
    for (int mt = 0; mt < 2; ++mt)
#pragma unroll
        for (int nt = 0; nt < 6; ++nt) {
            f32x4 a = {0.f, 0.f, 0.f, 0.f};
#pragma unroll
            for (int ks = 0; ks < 3; ++ks)
                a = __builtin_amdgcn_mfma_f32_16x16x32_bf16(
                        afrag[mt][ks], bfrag[nt][ks], a, 0, 0, 0);
            acc[mt][nt] = a;
        }

#pragma unroll
    for (int mt = 0; mt < 2; ++mt)
#pragma unroll
        for (int nt = 0; nt < 6; ++nt) {
            const int col = nt * 16 + ln;
            const long rowb = r0 + mt * 16 + kg * 4;
#pragma unroll
            for (int r = 0; r < 4; ++r)
                out[(rowb + r) * 96 + col] = acc[mt][nt][r] + bias[nt];
        }
}

// ---------------------------------------------------------------------------
// Fallback (round-1 fp32 kernel) if workspace is too small.
// ---------------------------------------------------------------------------
__global__ void winattn_fp32(const float* __restrict__ x,
                             const float* __restrict__ w_qkv,
                             const float* __restrict__ b_qkv,
                             const float* __restrict__ rel_pos,
                             const float* __restrict__ w_out,
                             const float* __restrict__ b_out,
                             float* __restrict__ out) {
    __shared__ float s_x[49][96];
    __shared__ float s_qkv[49][288];
    __shared__ float s_rel[3 * 169];
    const int t = threadIdx.x;
    const int blk = blockIdx.x;
    const int ww = blk & 7, hh = (blk >> 3) & 7, b = blk >> 6;
    for (int i = t; i < 3 * 169; i += 256) s_rel[i] = rel_pos[i];
    const float* xb = x + (size_t)b * 56 * 56 * 96;
    for (int i = t; i < 49 * 24; i += 256) {
        int tok = i / 24, ch4 = i % 24, p = tok / 7, q = tok % 7;
        float4 v = *(const float4*)(xb + (((p * 8 + hh) * 56) + (q * 8 + ww)) * 96 + ch4 * 4);
        *(float4*)(&s_x[tok][ch4 * 4]) = v;
    }
    __syncthreads();
    for (int u = t; u < 504; u += 256) {
        int cg = u % 72, rg = u / 72, col = cg * 4, r0 = rg * 7;
        float4 bq = *(const float4*)(b_qkv + col);
        float acc[7][4];
#pragma unroll
        for (int r = 0; r < 7; ++r) { acc[r][0]=bq.x; acc[r][1]=bq.y; acc[r][2]=bq.z; acc[r][3]=bq.w; }
        for (int k = 0; k < 96; k += 4) {
            float4 w0 = *(const float4*)(w_qkv + (size_t)(k+0)*288 + col);
            float4 w1 = *(const float4*)(w_qkv + (size_t)(k+1)*288 + col);
            float4 w2 = *(const float4*)(w_qkv + (size_t)(k+2)*288 + col);
            float4 w3 = *(const float4*)(w_qkv + (size_t)(k+3)*288 + col);
#pragma unroll
            for (int r = 0; r < 7; ++r) {
                float4 xv = *(const float4*)(&s_x[r0+r][k]);
                acc[r][0] += xv.x*w0.x + xv.y*w1.x + xv.z*w2.x + xv.w*w3.x;
                acc[r][1] += xv.x*w0.y + xv.y*w1.y + xv.z*w2.y + xv.w*w3.y;
                acc[r][2] += xv.x*w0.z + xv.y*w1.z + xv.z*w2.z + xv.w*w3.z;
                acc[r][3] += xv.x*w0.w + xv.y*w1.w + xv.z*w2.w + xv.w*w3.w;
            }
        }
#pragma unroll
        for (int r = 0; r < 7; ++r)
            *(float4*)(&s_qkv[r0+r][col]) = make_float4(acc[r][0],acc[r][1],acc[r][2],acc[r][3]);
    }
    __syncthreads();
    if (t < 147) {
        const int g = t / 49, qi = t - g * 49, pi = qi / 7, qq = qi - pi * 7;
        float qreg[32];
#pragma unroll
        for (int d = 0; d < 32; d += 4) {
            float4 v = *(const float4*)(&s_qkv[qi][g*32 + d]);
            qreg[d]=v.x*SCALE; qreg[d+1]=v.y*SCALE; qreg[d+2]=v.z*SCALE; qreg[d+3]=v.w*SCALE;
        }
        float sim[49]; float m = -1e30f;
        for (int j = 0; j < 49; ++j) {
            float a = 0.f;
            const float* kr = &s_qkv[j][96 + g*32];
#pragma unroll
            for (int d = 0; d < 32; d += 4) {
                float4 kv = *(const float4*)(kr + d);
                a += qreg[d]*kv.x + qreg[d+1]*kv.y + qreg[d+2]*kv.z + qreg[d+3]*kv.w;
            }
            int pj = j / 7, qj = j % 7;
            a += s_rel[g*169 + (pi-pj+6)*13 + (qq-qj+6)];
            sim[j] = a; m = fmaxf(m, a);
        }
        float s = 0.f;
        for (int j = 0; j < 49; ++j) { float e = __expf(sim[j]-m); sim[j]=e; s+=e; }
        float inv = 1.f/s;
        float o[32];
#pragma unroll
        for (int d = 0; d < 32; ++d) o[d] = 0.f;
        for (int j = 0; j < 49; ++j) {
            float p = sim[j];
            const float* vr = &s_qkv[j][192 + g*32];
#pragma unroll
            for (int d = 0; d < 32; d += 4) {
                float4 vv = *(const float4*)(vr + d);
                o[d] += p*vv.x; o[d+1] += p*vv.y; o[d+2] += p*vv.z; o[d+3] += p*vv.w;
            }
        }
#pragma unroll
        for (int d = 0; d < 32; d += 4)
            *(float4*)(&s_x[qi][g*32 + d]) = make_float4(o[d]*inv, o[d+1]*inv, o[d+2]*inv, o[d+3]*inv);
    }
    __syncthreads();
    for (int u = t; u < 336; u += 256) {
        int cg = u % 48, rg = u / 48, col = cg * 2, r0 = rg * 7;
        float b0 = b_out[col], b1 = b_out[col+1];
        float acc[7][2];
#pragma unroll
        for (int r = 0; r < 7; ++r) { acc[r][0]=b0; acc[r][1]=b1; }
        for (int k = 0; k < 96; k += 4) {
            float2 w0 = *(const float2*)(w_out + (size_t)(k+0)*96 + col);
            float2 w1 = *(const float2*)(w_out + (size_t)(k+1)*96 + col);
            float2 w2 = *(const float2*)(w_out + (size_t)(k+2)*96 + col);
            float2 w3 = *(const float2*)(w_out + (size_t)(k+3)*96 + col);
#pragma unroll
            for (int r = 0; r < 7; ++r) {
                float4 xv = *(const float4*)(&s_x[r0+r][k]);
                acc[r][0] += xv.x*w0.x + xv.y*w1.x + xv.z*w2.x + xv.w*w3.x;
                acc[r][1] += xv.x*w0.y + xv.y*w1.y + xv.z*w2.y + xv.w*w3.y;
            }
        }
#pragma unroll
        for (int r = 0; r < 7; ++r)
            *(float2*)(out + (size_t)(((b*56 + rg*8 + hh)*56) + r*8 + ww)*96 + col) =
                make_float2(acc[r][0], acc[r][1]);
    }
}

extern "C" void kernel_launch(void* const* d_in, const int* in_sizes, int n_in,
                              void* d_out, int out_size, void* d_ws, size_t ws_size,
                              hipStream_t stream) {
    const float* x       = (const float*)d_in[0];
    const float* w_qkv   = (const float*)d_in[1];
    const float* b_qkv   = (const float*)d_in[2];
    const float* rel_pos = (const float*)d_in[3];
    const float* w_out   = (const float*)d_in[4];
    const float* b_out   = (const float*)d_in[5];
    float* out = (float*)d_out;

    const size_t QKV_BYTES = (size_t)200704 * 288 * 2;   // 115,605,504
    const size_t AO_BYTES  = (size_t)200704 * 96 * 2;    //  38,535,168

    if (ws_size >= QKV_BYTES + AO_BYTES) {
        unsigned short* qkv = (unsigned short*)d_ws;
        unsigned short* ao  = (unsigned short*)((char*)d_ws + QKV_BYTES);
        hipLaunchKernelGGL(k_qkv,   dim3(4704), dim3(256), 0, stream, x, w_qkv, b_qkv, qkv);
        hipLaunchKernelGGL(k_attn,  dim3(4096), dim3(256), 0, stream, qkv, rel_pos, ao);
        hipLaunchKernelGGL(k_oproj, dim3(1568), dim3(256), 0, stream, ao, w_out, b_out, out);
    } else {
        hipLaunchKernelGGL(winattn_fp32, dim3(4096), dim3(256), 0, stream,
                           x, w_qkv, b_qkv, rel_pos, w_out, b_out, out);
    }
}

// Round 3
// 281.949 us; speedup vs baseline: 5.1861x; 2.0682x over previous
//
#include <hip/hip_runtime.h>
#include <math.h>

#define SCALE 0.17677669529663687f   // 32^-0.5

typedef float f32x4 __attribute__((ext_vector_type(4)));
typedef short s16x8 __attribute__((ext_vector_type(8)));
typedef short s16x4 __attribute__((ext_vector_type(4)));

__device__ __forceinline__ unsigned short f2bf(float f) {
    unsigned int u = __float_as_uint(f);
    u += 0x7fffu + ((u >> 16) & 1u);          // RNE
    return (unsigned short)(u >> 16);
}
__device__ __forceinline__ float bf2f(unsigned short u) {
    return __uint_as_float((unsigned int)u << 16);
}

// ---------------------------------------------------------------------------
// K0: one-time weight conversion to transposed bf16.
// wqT[c][k] (288x96), woT[c][k] (96x96): B-fragment loads become dwordx4.
// ---------------------------------------------------------------------------
__global__ void k_prep(const float* __restrict__ wq, const float* __restrict__ wo,
                       unsigned short* __restrict__ wqT, unsigned short* __restrict__ woT) {
    int i = blockIdx.x * 256 + threadIdx.x;
    if (i < 27648) {
        int c = i / 96, k = i - c * 96;
        wqT[i] = f2bf(wq[k * 288 + c]);
    } else if (i < 36864) {
        int t = i - 27648;
        int c = t / 96, k = t - c * 96;
        woT[t] = f2bf(wo[k * 96 + c]);
    }
}

// ---------------------------------------------------------------------------
// K1: QKV projection GEMM. M=200704, K=96, N=288, bf16 MFMA.
// Wave = 32 rows x 96 cols. B-frags = dwordx4 from transposed bf16 weights.
// ---------------------------------------------------------------------------
__global__ __launch_bounds__(256, 2) void k_qkv(
        const float* __restrict__ x, const unsigned short* __restrict__ wqT,
        const float* __restrict__ b_qkv, unsigned short* __restrict__ qkv) {
    const int lane = threadIdx.x & 63;
    const int wid  = blockIdx.x * 4 + (threadIdx.x >> 6);
    const int m2 = wid / 3;
    const int ng = wid - m2 * 3;
    const int ln = lane & 15;
    const int kg = lane >> 4;
    const int n0 = ng * 96;
    const long r0 = (long)m2 * 32;

    s16x8 bfrag[6][3];
    float bias[6];
#pragma unroll
    for (int nt = 0; nt < 6; ++nt) {
        const int col = n0 + nt * 16 + ln;
        bias[nt] = b_qkv[col];
#pragma unroll
        for (int ks = 0; ks < 3; ++ks)
            bfrag[nt][ks] = *(const s16x8*)(wqT + (size_t)col * 96 + ks * 32 + kg * 8);
    }
    s16x8 afrag[2][3];
#pragma unroll
    for (int mt = 0; mt < 2; ++mt) {
        const long m = r0 + mt * 16 + ln;
#pragma unroll
        for (int ks = 0; ks < 3; ++ks) {
            const float4 a0 = *(const float4*)(x + m * 96 + ks * 32 + kg * 8);
            const float4 a1 = *(const float4*)(x + m * 96 + ks * 32 + kg * 8 + 4);
            s16x8 f;
            f[0] = (short)f2bf(a0.x); f[1] = (short)f2bf(a0.y);
            f[2] = (short)f2bf(a0.z); f[3] = (short)f2bf(a0.w);
            f[4] = (short)f2bf(a1.x); f[5] = (short)f2bf(a1.y);
            f[6] = (short)f2bf(a1.z); f[7] = (short)f2bf(a1.w);
            afrag[mt][ks] = f;
        }
    }

    f32x4 acc[2][6];
#pragma unroll
    for (int mt = 0; mt < 2; ++mt)
#pragma unroll
        for (int nt = 0; nt < 6; ++nt) {
            f32x4 a = {0.f, 0.f, 0.f, 0.f};
#pragma unroll
            for (int ks = 0; ks < 3; ++ks)
                a = __builtin_amdgcn_mfma_f32_16x16x32_bf16(
                        afrag[mt][ks], bfrag[nt][ks], a, 0, 0, 0);
            acc[mt][nt] = a;
        }

#pragma unroll
    for (int mt = 0; mt < 2; ++mt)
#pragma unroll
        for (int nt = 0; nt < 6; ++nt) {
            const int col = n0 + nt * 16 + ln;
            const long rowb = r0 + mt * 16 + kg * 4;
#pragma unroll
            for (int r = 0; r < 4; ++r) {
                float v = acc[mt][nt][r] + bias[nt];
                if (ng == 0) v *= SCALE;
                qkv[(rowb + r) * 288 + col] = f2bf(v);
            }
        }
}

// ---------------------------------------------------------------------------
// K2: attention, one (window, head) per WAVE, MFMA.
// S = Q K^T: 16 x mfma_16x16x32 (d=32 = 1 k-step), softmax in C-layout regs,
// P -> LDS (bf16), V transposed -> LDS, O = P V: 16 MFMAs, repack, store.
// ---------------------------------------------------------------------------
#define PSTR 68   // P row stride in shorts (136 B, 8B-aligned b64 frags)
#define VSTR 68   // Vt row stride in shorts
#define OSTR 40   // O repack row stride in shorts (80 B, 16B-aligned)

__device__ __forceinline__ s16x8 ld_frag_b64(const unsigned short* p) {
    s16x4 lo = *(const s16x4*)(p);
    s16x4 hi = *(const s16x4*)(p + 4);
    return __builtin_shufflevector(lo, hi, 0, 1, 2, 3, 4, 5, 6, 7);
}

__global__ __launch_bounds__(256, 3) void k_attn(
        const unsigned short* __restrict__ qkv,
        const float* __restrict__ rel_pos,
        unsigned short* __restrict__ ao) {
    __shared__ unsigned short s_P[4][64 * PSTR];   // 8704 B per wave
    __shared__ unsigned short s_Vt[4][32 * VSTR];  // 4352 B per wave
    __shared__ unsigned short s_relb[508];         // bf16 bias table

    const int tid = threadIdx.x;
    const int wv = tid >> 6;
    const int lane = tid & 63;
    const int ln = lane & 15;
    const int kg = lane >> 4;

    for (int i = tid; i < 507; i += 256) s_relb[i] = f2bf(rel_pos[i]);

    const int task = blockIdx.x * 4 + wv;
    const int win = task / 3;
    const int g = task - win * 3;
    const int ww = win & 7, hh = (win >> 3) & 7, b = win >> 6;
    const size_t base = (size_t)b * 3136;

    // ---- stage V transposed: Vt[d][j] ----
    unsigned short* Vt = s_Vt[wv];
    if (lane < 49) {
        const int p = lane / 7, q = lane - p * 7;
        const size_t pix = base + (p * 8 + hh) * 56 + (q * 8 + ww);
        const uint4* vp = (const uint4*)(qkv + pix * 288 + 192 + g * 32);
#pragma unroll
        for (int c = 0; c < 4; ++c) {
            uint4 u = vp[c];
            Vt[(c*8+0)*VSTR + lane] = (unsigned short)(u.x & 0xffffu);
            Vt[(c*8+1)*VSTR + lane] = (unsigned short)(u.x >> 16);
            Vt[(c*8+2)*VSTR + lane] = (unsigned short)(u.y & 0xffffu);
            Vt[(c*8+3)*VSTR + lane] = (unsigned short)(u.y >> 16);
            Vt[(c*8+4)*VSTR + lane] = (unsigned short)(u.z & 0xffffu);
            Vt[(c*8+5)*VSTR + lane] = (unsigned short)(u.z >> 16);
            Vt[(c*8+6)*VSTR + lane] = (unsigned short)(u.w & 0xffffu);
            Vt[(c*8+7)*VSTR + lane] = (unsigned short)(u.w >> 16);
        }
    }
    // zero pad columns j = 49..63 (avoid NaN garbage into PV)
    for (int i = lane; i < 32 * 15; i += 64) {
        int d = i / 15, j = 49 + (i - d * 15);
        Vt[d * VSTR + j] = 0;
    }

    // ---- Q/K fragments straight from global ----
    s16x8 qf[4], kf[4];
#pragma unroll
    for (int mt = 0; mt < 4; ++mt) {
        int tok = mt * 16 + ln; if (tok > 48) tok = 48;
        const int p = tok / 7, q = tok - p * 7;
        const size_t pix = base + (p * 8 + hh) * 56 + (q * 8 + ww);
        qf[mt] = *(const s16x8*)(qkv + pix * 288 + g * 32 + kg * 8);
        kf[mt] = *(const s16x8*)(qkv + pix * 288 + 96 + g * 32 + kg * 8);
    }

    __syncthreads();   // s_relb ready

    // ---- S = Q K^T ----
    f32x4 sacc[4][4];
#pragma unroll
    for (int mt = 0; mt < 4; ++mt)
#pragma unroll
        for (int nt = 0; nt < 4; ++nt) {
            f32x4 z = {0.f, 0.f, 0.f, 0.f};
            sacc[mt][nt] = __builtin_amdgcn_mfma_f32_16x16x32_bf16(
                               qf[mt], kf[nt], z, 0, 0, 0);
        }

    // ---- bias + mask ----
    int aRow[4][4];
#pragma unroll
    for (int mt = 0; mt < 4; ++mt)
#pragma unroll
        for (int r = 0; r < 4; ++r) {
            int qq = mt * 16 + kg * 4 + r;
            int pi = qq / 7;
            aRow[mt][r] = pi * 13 + (qq - pi * 7);
        }
    int bCol[4];
#pragma unroll
    for (int nt = 0; nt < 4; ++nt) {
        int j = nt * 16 + ln;
        int pj = j / 7;
        bCol[nt] = pj * 13 + (j - pj * 7);
    }
#pragma unroll
    for (int nt = 0; nt < 4; ++nt) {
        const int j = nt * 16 + ln;
        const bool val = (j < 49);
#pragma unroll
        for (int mt = 0; mt < 4; ++mt)
#pragma unroll
            for (int r = 0; r < 4; ++r) {
                int idx = val ? (g * 169 + aRow[mt][r] - bCol[nt] + 84) : 0;
                float bb = bf2f(s_relb[idx]);
                sacc[mt][nt][r] = val ? (sacc[mt][nt][r] + bb) : -3e38f;
            }
    }

    // ---- softmax (rows spread over 16-lane groups) ----
    float rm[4][4], rs[4][4];
#pragma unroll
    for (int mt = 0; mt < 4; ++mt)
#pragma unroll
        for (int r = 0; r < 4; ++r) {
            float m = fmaxf(fmaxf(sacc[mt][0][r], sacc[mt][1][r]),
                            fmaxf(sacc[mt][2][r], sacc[mt][3][r]));
            m = fmaxf(m, __shfl_xor(m, 1));
            m = fmaxf(m, __shfl_xor(m, 2));
            m = fmaxf(m, __shfl_xor(m, 4));
            m = fmaxf(m, __shfl_xor(m, 8));
            rm[mt][r] = m;
        }
    unsigned short* P = s_P[wv];
#pragma unroll
    for (int mt = 0; mt < 4; ++mt) {
#pragma unroll
        for (int r = 0; r < 4; ++r) rs[mt][r] = 0.f;
#pragma unroll
        for (int nt = 0; nt < 4; ++nt) {
            const int j = nt * 16 + ln;
#pragma unroll
            for (int r = 0; r < 4; ++r) {
                float e = __expf(sacc[mt][nt][r] - rm[mt][r]);
                rs[mt][r] += e;
                P[(mt * 16 + kg * 4 + r) * PSTR + j] = f2bf(e);
            }
        }
#pragma unroll
        for (int r = 0; r < 4; ++r) {
            float s = rs[mt][r];
            s += __shfl_xor(s, 1);
            s += __shfl_xor(s, 2);
            s += __shfl_xor(s, 4);
            s += __shfl_xor(s, 8);
            rs[mt][r] = s;
        }
    }

    // ---- O = P V ----  (same-wave DS ops execute in order: no barrier needed)
    s16x8 pf[4][2], vf[2][2];
#pragma unroll
    for (int mt = 0; mt < 4; ++mt)
#pragma unroll
        for (int ks = 0; ks < 2; ++ks)
            pf[mt][ks] = ld_frag_b64(P + (mt * 16 + ln) * PSTR + ks * 32 + kg * 8);
#pragma unroll
    for (int nt = 0; nt < 2; ++nt)
#pragma unroll
        for (int ks = 0; ks < 2; ++ks)
            vf[nt][ks] = ld_frag_b64(Vt + (nt * 16 + ln) * VSTR + ks * 32 + kg * 8);

    f32x4 oacc[4][2];
#pragma unroll
    for (int mt = 0; mt < 4; ++mt)
#pragma unroll
        for (int nt = 0; nt < 2; ++nt) {
            f32x4 a = {0.f, 0.f, 0.f, 0.f};
#pragma unroll
            for (int ks = 0; ks < 2; ++ks)
                a = __builtin_amdgcn_mfma_f32_16x16x32_bf16(
                        pf[mt][ks], vf[nt][ks], a, 0, 0, 0);
            oacc[mt][nt] = a;
        }

    // ---- normalize + repack (reuse P region) + coalesced store ----
#pragma unroll
    for (int mt = 0; mt < 4; ++mt)
#pragma unroll
        for (int r = 0; r < 4; ++r) {
            const int qq = mt * 16 + kg * 4 + r;
            if (qq < 49) {
                const float inv = 1.f / rs[mt][r];
#pragma unroll
                for (int nt = 0; nt < 2; ++nt)
                    P[qq * OSTR + nt * 16 + ln] = f2bf(oacc[mt][nt][r] * inv);
            }
        }
    if (lane < 49) {
        const int p = lane / 7, q = lane - p * 7;
        const size_t pix = base + (p * 8 + hh) * 56 + (q * 8 + ww);
        uint4* dst = (uint4*)(ao + pix * 96 + g * 32);
        const uint4* src = (const uint4*)(P + lane * OSTR);
#pragma unroll
        for (int c = 0; c < 4; ++c) dst[c] = src[c];
    }
}

// ---------------------------------------------------------------------------
// K3: output projection GEMM. M=200704, K=96, N=96, A raw bf16, fp32 out.
// ---------------------------------------------------------------------------
__global__ __launch_bounds__(256, 2) void k_oproj(
        const unsigned short* __restrict__ ao, const unsigned short* __restrict__ woT,
        const float* __restrict__ b_out, float* __restrict__ out) {
    const int lane = threadIdx.x & 63;
    const int m2 = blockIdx.x * 4 + (threadIdx.x >> 6);
    const int ln = lane & 15;
    const int kg = lane >> 4;
    const long r0 = (long)m2 * 32;

    s16x8 bfrag[6][3];
    float bias[6];
#pragma unroll
    for (int nt = 0; nt < 6; ++nt) {
        const int col = nt * 16 + ln;
        bias[nt] = b_out[col];
#pragma unroll
        for (int ks = 0; ks < 3; ++ks)
            bfrag[nt][ks] = *(const s16x8*)(woT + (size_t)col * 96 + ks * 32 + kg * 8);
    }
    s16x8 afrag[2][3];
#pragma unroll
    for (int mt = 0; mt < 2; ++mt) {
        const long m = r0 + mt * 16 + ln;
#pragma unroll
        for (int ks = 0; ks < 3; ++ks)
            afrag[mt][ks] = *(const s16x8*)(ao + m * 96 + ks * 32 + kg * 8);
    }

    f32x4 acc[2][6];
#pragma unroll
    for (int mt = 0; mt < 2; ++mt)
#pragma unroll
        for (int nt = 0; nt < 6; ++nt) {
            f32x4 a = {0.f, 0.f, 0.f, 0.f};
#pragma unroll
            for (int ks = 0; ks < 3; ++ks)
                a = __builtin_amdgcn_mfma_f32_16x16x32_bf16(
                        afrag[mt][ks], bfrag[nt][ks], a, 0, 0, 0);
            acc[mt][nt] = a;
        }

#pragma unroll
    for (int mt = 0; mt < 2; ++mt)
#pragma unroll
        for (int nt = 0; nt < 6; ++nt) {
            const int col = nt * 16 + ln;
            const long rowb = r0 + mt * 16 + kg * 4;
#pragma unroll
            for (int r = 0; r < 4; ++r)
                out[(rowb + r) * 96 + col] = acc[mt][nt][r] + bias[nt];
        }
}

// ---------------------------------------------------------------------------
// Fallback (round-1 fp32 monolith) if workspace is too small.
// ---------------------------------------------------------------------------
__global__ void winattn_fp32(const float* __restrict__ x,
                             const float* __restrict__ w_qkv,
                             const float* __restrict__ b_qkv,
                             const float* __restrict__ rel_pos,
                             const float* __restrict__ w_out,
                             const float* __restrict__ b_out,
                             float* __restrict__ out) {
    __shared__ float s_x[49][96];
    __shared__ float s_qkv[49][288];
    __shared__ float s_rel[3 * 169];
    const int t = threadIdx.x;
    const int blk = blockIdx.x;
    const int ww = blk & 7, hh = (blk >> 3) & 7, b = blk >> 6;
    for (int i = t; i < 3 * 169; i += 256) s_rel[i] = rel_pos[i];
    const float* xb = x + (size_t)b * 56 * 56 * 96;
    for (int i = t; i < 49 * 24; i += 256) {
        int tok = i / 24, ch4 = i % 24, p = tok / 7, q = tok % 7;
        float4 v = *(const float4*)(xb + (((p * 8 + hh) * 56) + (q * 8 + ww)) * 96 + ch4 * 4);
        *(float4*)(&s_x[tok][ch4 * 4]) = v;
    }
    __syncthreads();
    for (int u = t; u < 504; u += 256) {
        int cg = u % 72, rg = u / 72, col = cg * 4, r0 = rg * 7;
        float4 bq = *(const float4*)(b_qkv + col);
        float acc[7][4];
#pragma unroll
        for (int r = 0; r < 7; ++r) { acc[r][0]=bq.x; acc[r][1]=bq.y; acc[r][2]=bq.z; acc[r][3]=bq.w; }
        for (int k = 0; k < 96; k += 4) {
            float4 w0 = *(const float4*)(w_qkv + (size_t)(k+0)*288 + col);
            float4 w1 = *(const float4*)(w_qkv + (size_t)(k+1)*288 + col);
            float4 w2 = *(const float4*)(w_qkv + (size_t)(k+2)*288 + col);
            float4 w3 = *(const float4*)(w_qkv + (size_t)(k+3)*288 + col);
#pragma unroll
            for (int r = 0; r < 7; ++r) {
                float4 xv = *(const float4*)(&s_x[r0+r][k]);
                acc[r][0] += xv.x*w0.x + xv.y*w1.x + xv.z*w2.x + xv.w*w3.x;
                acc[r][1] += xv.x*w0.y + xv.y*w1.y + xv.z*w2.y + xv.w*w3.y;
                acc[r][2] += xv.x*w0.z + xv.y*w1.z + xv.z*w2.z + xv.w*w3.z;
                acc[r][3] += xv.x*w0.w + xv.y*w1.w + xv.z*w2.w + xv.w*w3.w;
            }
        }
#pragma unroll
        for (int r = 0; r < 7; ++r)
            *(float4*)(&s_qkv[r0+r][col]) = make_float4(acc[r][0],acc[r][1],acc[r][2],acc[r][3]);
    }
    __syncthreads();
    if (t < 147) {
        const int g = t / 49, qi = t - g * 49, pi = qi / 7, qq = qi - pi * 7;
        float qreg[32];
#pragma unroll
        for (int d = 0; d < 32; d += 4) {
            float4 v = *(const float4*)(&s_qkv[qi][g*32 + d]);
            qreg[d]=v.x*SCALE; qreg[d+1]=v.y*SCALE; qreg[d+2]=v.z*SCALE; qreg[d+3]=v.w*SCALE;
        }
        float sim[49]; float m = -1e30f;
        for (int j = 0; j < 49; ++j) {
            float a = 0.f;
            const float* kr = &s_qkv[j][96 + g*32];
#pragma unroll
            for (int d = 0; d < 32; d += 4) {
                float4 kv = *(const float4*)(kr + d);
                a += qreg[d]*kv.x + qreg[d+1]*kv.y + qreg[d+2]*kv.z + qreg[d+3]*kv.w;
            }
            int pj = j / 7, qj = j % 7;
            a += s_rel[g*169 + (pi-pj+6)*13 + (qq-qj+6)];
            sim[j] = a; m = fmaxf(m, a);
        }
        float s = 0.f;
        for (int j = 0; j < 49; ++j) { float e = __expf(sim[j]-m); sim[j]=e; s+=e; }
        float inv = 1.f/s;
        float o[32];
#pragma unroll
        for (int d = 0; d < 32; ++d) o[d] = 0.f;
        for (int j = 0; j < 49; ++j) {
            float p = sim[j];
            const float* vr = &s_qkv[j][192 + g*32];
#pragma unroll
            for (int d = 0; d < 32; d += 4) {
                float4 vv = *(const float4*)(vr + d);
                o[d] += p*vv.x; o[d+1] += p*vv.y; o[d+2] += p*vv.z; o[d+3] += p*vv.w;
            }
        }
#pragma unroll
        for (int d = 0; d < 32; d += 4)
            *(float4*)(&s_x[qi][g*32 + d]) = make_float4(o[d]*inv, o[d+1]*inv, o[d+2]*inv, o[d+3]*inv);
    }
    __syncthreads();
    for (int u = t; u < 336; u += 256) {
        int cg = u % 48, rg = u / 48, col = cg * 2, r0 = rg * 7;
        float b0 = b_out[col], b1 = b_out[col+1];
        float acc[7][2];
#pragma unroll
        for (int r = 0; r < 7; ++r) { acc[r][0]=b0; acc[r][1]=b1; }
        for (int k = 0; k < 96; k += 4) {
            float2 w0 = *(const float2*)(w_out + (size_t)(k+0)*96 + col);
            float2 w1 = *(const float2*)(w_out + (size_t)(k+1)*96 + col);
            float2 w2 = *(const float2*)(w_out + (size_t)(k+2)*96 + col);
            float2 w3 = *(const float2*)(w_out + (size_t)(k+3)*96 + col);
#pragma unroll
            for (int r = 0; r < 7; ++r) {
                float4 xv = *(const float4*)(&s_x[r0+r][k]);
                acc[r][0] += xv.x*w0.x + xv.y*w1.x + xv.z*w2.x + xv.w*w3.x;
                acc[r][1] += xv.x*w0.y + xv.y*w1.y + xv.z*w2.y + xv.w*w3.y;
            }
        }
#pragma unroll
        for (int r = 0; r < 7; ++r)
            *(float2*)(out + (size_t)(((b*56 + rg*8 + hh)*56) + r*8 + ww)*96 + col) =
                make_float2(acc[r][0], acc[r][1]);
    }
}

extern "C" void kernel_launch(void* const* d_in, const int* in_sizes, int n_in,
                              void* d_out, int out_size, void* d_ws, size_t ws_size,
                              hipStream_t stream) {
    const float* x       = (const float*)d_in[0];
    const float* w_qkv   = (const float*)d_in[1];
    const float* b_qkv   = (const float*)d_in[2];
    const float* rel_pos = (const float*)d_in[3];
    const float* w_out   = (const float*)d_in[4];
    const float* b_out   = (const float*)d_in[5];
    float* out = (float*)d_out;

    const size_t QKV_BYTES = (size_t)200704 * 288 * 2;   // 115,605,504
    const size_t AO_BYTES  = (size_t)200704 * 96 * 2;    //  38,535,168
    const size_t WQT_BYTES = (size_t)288 * 96 * 2;       //  55,296
    const size_t WOT_BYTES = (size_t)96 * 96 * 2;        //  18,432

    if (ws_size >= QKV_BYTES + AO_BYTES + WQT_BYTES + WOT_BYTES) {
        unsigned short* qkv = (unsigned short*)d_ws;
        unsigned short* ao  = (unsigned short*)((char*)d_ws + QKV_BYTES);
        unsigned short* wqT = (unsigned short*)((char*)d_ws + QKV_BYTES + AO_BYTES);
        unsigned short* woT = (unsigned short*)((char*)d_ws + QKV_BYTES + AO_BYTES + WQT_BYTES);
        hipLaunchKernelGGL(k_prep,  dim3(144),  dim3(256), 0, stream, w_qkv, w_out, wqT, woT);
        hipLaunchKernelGGL(k_qkv,   dim3(4704), dim3(256), 0, stream, x, wqT, b_qkv, qkv);
        hipLaunchKernelGGL(k_attn,  dim3(3072), dim3(256), 0, stream, qkv, rel_pos, ao);
        hipLaunchKernelGGL(k_oproj, dim3(1568), dim3(256), 0, stream, ao, woT, b_out, out);
    } else {
        hipLaunchKernelGGL(winattn_fp32, dim3(4096), dim3(256), 0, stream,
                           x, w_qkv, b_qkv, rel_pos, w_out, b_out, out);
    }
}

// Round 4
// 244.427 us; speedup vs baseline: 5.9823x; 1.1535x over previous
//
#include <hip/hip_runtime.h>
#include <math.h>

#define SCALE 0.17677669529663687f   // 32^-0.5

typedef float f32x4 __attribute__((ext_vector_type(4)));
typedef short s16x8 __attribute__((ext_vector_type(8)));
typedef short s16x4 __attribute__((ext_vector_type(4)));

__device__ __forceinline__ unsigned short f2bf(float f) {
    unsigned int u = __float_as_uint(f);
    u += 0x7fffu + ((u >> 16) & 1u);          // RNE
    return (unsigned short)(u >> 16);
}
__device__ __forceinline__ float bf2f(unsigned short u) {
    return __uint_as_float((unsigned int)u << 16);
}
__device__ __forceinline__ s16x8 ld_frag_b64(const unsigned short* p) {
    s16x4 lo = *(const s16x4*)(p);
    s16x4 hi = *(const s16x4*)(p + 4);
    return __builtin_shufflevector(lo, hi, 0, 1, 2, 3, 4, 5, 6, 7);
}

// ---------------------------------------------------------------------------
// K0: one-time weight conversion to transposed bf16.
// wqT[c][k] (288x96), woT[c][k] (96x96): B-fragment loads become dwordx4.
// ---------------------------------------------------------------------------
__global__ void k_prep(const float* __restrict__ wq, const float* __restrict__ wo,
                       unsigned short* __restrict__ wqT, unsigned short* __restrict__ woT) {
    int i = blockIdx.x * 256 + threadIdx.x;
    if (i < 27648) {
        int c = i / 96, k = i - c * 96;
        wqT[i] = f2bf(wq[k * 288 + c]);
    } else if (i < 36864) {
        int t = i - 27648;
        int c = t / 96, k = t - c * 96;
        woT[t] = f2bf(wo[k * 96 + c]);
    }
}

// ---------------------------------------------------------------------------
// K1: fully fused per-window kernel. One block (256 thr) per window.
// Phase A: stage x (bf16) -> LDS. Phase B: QKV GEMM (LDS->LDS).
// Phase C: per-head wave-MFMA attention (R3-verified structure, LDS sources).
// Phase D: out-proj GEMM, scatter fp32 to global.
// ---------------------------------------------------------------------------
#define XSTR 104   // x/ao row stride (shorts): 208 B, 16B-aligned, 2-way-free
#define QSTR 296   // qkv row stride (shorts): 592 B, 16B-aligned, 2-way-free
#define PSTR 68
#define VSTR 68

__global__ __launch_bounds__(256, 2) void k_fused(
        const float* __restrict__ x,
        const unsigned short* __restrict__ wqT,
        const float* __restrict__ b_qkv,
        const float* __restrict__ rel_pos,
        const unsigned short* __restrict__ woT,
        const float* __restrict__ b_out,
        float* __restrict__ out) {
    __shared__ unsigned short s_qkv[49 * QSTR];    // 29008 B
    __shared__ unsigned short s_xb[49 * XSTR];     // 10192 B (x bf16; later ao)
    __shared__ unsigned short s_P[3][64 * PSTR];   // 26112 B
    __shared__ unsigned short s_Vt[3][32 * VSTR];  // 13056 B
    __shared__ unsigned short s_relb[508];         //  1016 B   (total ~79.4 KB)

    const int tid = threadIdx.x;
    const int wv = tid >> 6;
    const int lane = tid & 63;
    const int ln = lane & 15;
    const int kg = lane >> 4;

    const int win = blockIdx.x;
    const int ww = win & 7, hh = (win >> 3) & 7, b = win >> 6;
    const size_t base = (size_t)b * 3136;

    for (int i = tid; i < 507; i += 256) s_relb[i] = f2bf(rel_pos[i]);

    // ---- Phase A: stage x window as bf16 ----
    for (int i = tid; i < 1176; i += 256) {
        const int tok = i / 24, c = i - tok * 24;
        const int p = tok / 7, q = tok - p * 7;
        const float4 v = *(const float4*)(x + (base + (p * 8 + hh) * 56 + q * 8 + ww) * 96 + c * 4);
        uint2 u;
        u.x = (unsigned)f2bf(v.x) | ((unsigned)f2bf(v.y) << 16);
        u.y = (unsigned)f2bf(v.z) | ((unsigned)f2bf(v.w) << 16);
        *(uint2*)(s_xb + tok * XSTR + c * 4) = u;
    }
    __syncthreads();

    // ---- Phase B: QKV GEMM. M=49(->64), N=288, K=96 ----
    // wave nt0: {0,5,9,13}, 5 tiles each (tiles 9,13 duplicated: benign identical writes)
    {
        const int nt0 = (wv == 0) ? 0 : (wv == 1) ? 5 : (wv == 2) ? 9 : 13;
        s16x8 bfrag[5][3];
        float bias[5];
#pragma unroll
        for (int t = 0; t < 5; ++t) {
            const int col = (nt0 + t) * 16 + ln;
            bias[t] = b_qkv[col];
#pragma unroll
            for (int ks = 0; ks < 3; ++ks)
                bfrag[t][ks] = *(const s16x8*)(wqT + (size_t)col * 96 + ks * 32 + kg * 8);
        }
        s16x8 afrag[4][3];
#pragma unroll
        for (int mt = 0; mt < 4; ++mt) {
            int tok = mt * 16 + ln; if (tok > 48) tok = 48;
#pragma unroll
            for (int ks = 0; ks < 3; ++ks)
                afrag[mt][ks] = *(const s16x8*)(s_xb + tok * XSTR + ks * 32 + kg * 8);
        }
#pragma unroll
        for (int mt = 0; mt < 4; ++mt)
#pragma unroll
            for (int t = 0; t < 5; ++t) {
                f32x4 a = {0.f, 0.f, 0.f, 0.f};
#pragma unroll
                for (int ks = 0; ks < 3; ++ks)
                    a = __builtin_amdgcn_mfma_f32_16x16x32_bf16(
                            afrag[mt][ks], bfrag[t][ks], a, 0, 0, 0);
                const int col = (nt0 + t) * 16 + ln;
#pragma unroll
                for (int r = 0; r < 4; ++r) {
                    const int row = mt * 16 + kg * 4 + r;
                    float v = a[r] + bias[t];
                    if (col < 96) v *= SCALE;          // q section pre-scaled
                    if (row < 49) s_qkv[row * QSTR + col] = f2bf(v);
                }
            }
    }
    __syncthreads();

    // ---- Phase C: attention, wave g = head g (waves 0..2) ----
    if (wv < 3) {
        const int g = wv;
        unsigned short* Vt = s_Vt[g];
        if (lane < 49) {
            const unsigned short* vr = s_qkv + lane * QSTR + 192 + g * 32;
#pragma unroll
            for (int c = 0; c < 4; ++c) {
                uint4 u = *(const uint4*)(vr + c * 8);
                Vt[(c*8+0)*VSTR + lane] = (unsigned short)(u.x & 0xffffu);
                Vt[(c*8+1)*VSTR + lane] = (unsigned short)(u.x >> 16);
                Vt[(c*8+2)*VSTR + lane] = (unsigned short)(u.y & 0xffffu);
                Vt[(c*8+3)*VSTR + lane] = (unsigned short)(u.y >> 16);
                Vt[(c*8+4)*VSTR + lane] = (unsigned short)(u.z & 0xffffu);
                Vt[(c*8+5)*VSTR + lane] = (unsigned short)(u.z >> 16);
                Vt[(c*8+6)*VSTR + lane] = (unsigned short)(u.w & 0xffffu);
                Vt[(c*8+7)*VSTR + lane] = (unsigned short)(u.w >> 16);
            }
        }
        for (int i = lane; i < 32 * 15; i += 64) {
            int d = i / 15, j = 49 + (i - d * 15);
            Vt[d * VSTR + j] = 0;
        }

        s16x8 qf[4], kf[4];
#pragma unroll
        for (int mt = 0; mt < 4; ++mt) {
            int tok = mt * 16 + ln; if (tok > 48) tok = 48;
            qf[mt] = *(const s16x8*)(s_qkv + tok * QSTR + g * 32 + kg * 8);
            kf[mt] = *(const s16x8*)(s_qkv + tok * QSTR + 96 + g * 32 + kg * 8);
        }

        f32x4 sacc[4][4];
#pragma unroll
        for (int mt = 0; mt < 4; ++mt)
#pragma unroll
            for (int nt = 0; nt < 4; ++nt) {
                f32x4 z = {0.f, 0.f, 0.f, 0.f};
                sacc[mt][nt] = __builtin_amdgcn_mfma_f32_16x16x32_bf16(
                                   qf[mt], kf[nt], z, 0, 0, 0);
            }

        int aRow[4][4];
#pragma unroll
        for (int mt = 0; mt < 4; ++mt)
#pragma unroll
            for (int r = 0; r < 4; ++r) {
                int qq = mt * 16 + kg * 4 + r;
                int pi = qq / 7;
                aRow[mt][r] = pi * 13 + (qq - pi * 7);
            }
        int bCol[4];
#pragma unroll
        for (int nt = 0; nt < 4; ++nt) {
            int j = nt * 16 + ln;
            int pj = j / 7;
            bCol[nt] = pj * 13 + (j - pj * 7);
        }
#pragma unroll
        for (int nt = 0; nt < 4; ++nt) {
            const int j = nt * 16 + ln;
            const bool val = (j < 49);
#pragma unroll
            for (int mt = 0; mt < 4; ++mt)
#pragma unroll
                for (int r = 0; r < 4; ++r) {
                    int idx = val ? (g * 169 + aRow[mt][r] - bCol[nt] + 84) : 0;
                    float bb = bf2f(s_relb[idx]);
                    sacc[mt][nt][r] = val ? (sacc[mt][nt][r] + bb) : -3e38f;
                }
        }

        float rm[4][4], rs[4][4];
#pragma unroll
        for (int mt = 0; mt < 4; ++mt)
#pragma unroll
            for (int r = 0; r < 4; ++r) {
                float m = fmaxf(fmaxf(sacc[mt][0][r], sacc[mt][1][r]),
                                fmaxf(sacc[mt][2][r], sacc[mt][3][r]));
                m = fmaxf(m, __shfl_xor(m, 1));
                m = fmaxf(m, __shfl_xor(m, 2));
                m = fmaxf(m, __shfl_xor(m, 4));
                m = fmaxf(m, __shfl_xor(m, 8));
                rm[mt][r] = m;
            }
        unsigned short* P = s_P[g];
#pragma unroll
        for (int mt = 0; mt < 4; ++mt) {
#pragma unroll
            for (int r = 0; r < 4; ++r) rs[mt][r] = 0.f;
#pragma unroll
            for (int nt = 0; nt < 4; ++nt) {
                const int j = nt * 16 + ln;
#pragma unroll
                for (int r = 0; r < 4; ++r) {
                    float e = __expf(sacc[mt][nt][r] - rm[mt][r]);
                    rs[mt][r] += e;
                    P[(mt * 16 + kg * 4 + r) * PSTR + j] = f2bf(e);
                }
            }
#pragma unroll
            for (int r = 0; r < 4; ++r) {
                float s = rs[mt][r];
                s += __shfl_xor(s, 1);
                s += __shfl_xor(s, 2);
                s += __shfl_xor(s, 4);
                s += __shfl_xor(s, 8);
                rs[mt][r] = s;
            }
        }

        // O = P V   (same-wave DS ordering: no barrier needed)
        s16x8 pf[4][2], vf[2][2];
#pragma unroll
        for (int mt = 0; mt < 4; ++mt)
#pragma unroll
            for (int ks = 0; ks < 2; ++ks)
                pf[mt][ks] = ld_frag_b64(P + (mt * 16 + ln) * PSTR + ks * 32 + kg * 8);
#pragma unroll
        for (int nt = 0; nt < 2; ++nt)
#pragma unroll
            for (int ks = 0; ks < 2; ++ks)
                vf[nt][ks] = ld_frag_b64(Vt + (nt * 16 + ln) * VSTR + ks * 32 + kg * 8);

        f32x4 oacc[4][2];
#pragma unroll
        for (int mt = 0; mt < 4; ++mt)
#pragma unroll
            for (int nt = 0; nt < 2; ++nt) {
                f32x4 a = {0.f, 0.f, 0.f, 0.f};
#pragma unroll
                for (int ks = 0; ks < 2; ++ks)
                    a = __builtin_amdgcn_mfma_f32_16x16x32_bf16(
                            pf[mt][ks], vf[nt][ks], a, 0, 0, 0);
                oacc[mt][nt] = a;
            }

        // normalize + write ao (bf16) into s_xb cols g*32..g*32+31
#pragma unroll
        for (int mt = 0; mt < 4; ++mt)
#pragma unroll
            for (int r = 0; r < 4; ++r) {
                const int qq = mt * 16 + kg * 4 + r;
                if (qq < 49) {
                    const float inv = 1.f / rs[mt][r];
#pragma unroll
                    for (int nt = 0; nt < 2; ++nt)
                        s_xb[qq * XSTR + g * 32 + nt * 16 + ln] =
                            f2bf(oacc[mt][nt][r] * inv);
                }
            }
    }
    __syncthreads();

    // ---- Phase D: out-proj. wave = m-tile. M=49(->64), N=96, K=96 ----
    {
        const int mt = wv;
        s16x8 bfrag[6][3];
        float bias2[6];
#pragma unroll
        for (int nt = 0; nt < 6; ++nt) {
            const int col = nt * 16 + ln;
            bias2[nt] = b_out[col];
#pragma unroll
            for (int ks = 0; ks < 3; ++ks)
                bfrag[nt][ks] = *(const s16x8*)(woT + (size_t)col * 96 + ks * 32 + kg * 8);
        }
        int tok = mt * 16 + ln; if (tok > 48) tok = 48;
        s16x8 afrag[3];
#pragma unroll
        for (int ks = 0; ks < 3; ++ks)
            afrag[ks] = *(const s16x8*)(s_xb + tok * XSTR + ks * 32 + kg * 8);

#pragma unroll
        for (int nt = 0; nt < 6; ++nt) {
            f32x4 a = {0.f, 0.f, 0.f, 0.f};
#pragma unroll
            for (int ks = 0; ks < 3; ++ks)
                a = __builtin_amdgcn_mfma_f32_16x16x32_bf16(
                        afrag[ks], bfrag[nt][ks], a, 0, 0, 0);
#pragma unroll
            for (int r = 0; r < 4; ++r) {
                const int row = mt * 16 + kg * 4 + r;
                if (row < 49) {
                    const int p = row / 7, q = row - p * 7;
                    out[(base + (p * 8 + hh) * 56 + q * 8 + ww) * 96 + nt * 16 + ln] =
                        a[r] + bias2[nt];
                }
            }
        }
    }
}

// ---------------------------------------------------------------------------
// Fallback (round-1 fp32 monolith) if workspace is too small.
// ---------------------------------------------------------------------------
__global__ void winattn_fp32(const float* __restrict__ x,
                             const float* __restrict__ w_qkv,
                             const float* __restrict__ b_qkv,
                             const float* __restrict__ rel_pos,
                             const float* __restrict__ w_out,
                             const float* __restrict__ b_out,
                             float* __restrict__ out) {
    __shared__ float s_x[49][96];
    __shared__ float s_qkv[49][288];
    __shared__ float s_rel[3 * 169];
    const int t = threadIdx.x;
    const int blk = blockIdx.x;
    const int ww = blk & 7, hh = (blk >> 3) & 7, b = blk >> 6;
    for (int i = t; i < 3 * 169; i += 256) s_rel[i] = rel_pos[i];
    const float* xb = x + (size_t)b * 56 * 56 * 96;
    for (int i = t; i < 49 * 24; i += 256) {
        int tok = i / 24, ch4 = i % 24, p = tok / 7, q = tok % 7;
        float4 v = *(const float4*)(xb + (((p * 8 + hh) * 56) + (q * 8 + ww)) * 96 + ch4 * 4);
        *(float4*)(&s_x[tok][ch4 * 4]) = v;
    }
    __syncthreads();
    for (int u = t; u < 504; u += 256) {
        int cg = u % 72, rg = u / 72, col = cg * 4, r0 = rg * 7;
        float4 bq = *(const float4*)(b_qkv + col);
        float acc[7][4];
#pragma unroll
        for (int r = 0; r < 7; ++r) { acc[r][0]=bq.x; acc[r][1]=bq.y; acc[r][2]=bq.z; acc[r][3]=bq.w; }
        for (int k = 0; k < 96; k += 4) {
            float4 w0 = *(const float4*)(w_qkv + (size_t)(k+0)*288 + col);
            float4 w1 = *(const float4*)(w_qkv + (size_t)(k+1)*288 + col);
            float4 w2 = *(const float4*)(w_qkv + (size_t)(k+2)*288 + col);
            float4 w3 = *(const float4*)(w_qkv + (size_t)(k+3)*288 + col);
#pragma unroll
            for (int r = 0; r < 7; ++r) {
                float4 xv = *(const float4*)(&s_x[r0+r][k]);
                acc[r][0] += xv.x*w0.x + xv.y*w1.x + xv.z*w2.x + xv.w*w3.x;
                acc[r][1] += xv.x*w0.y + xv.y*w1.y + xv.z*w2.y + xv.w*w3.y;
                acc[r][2] += xv.x*w0.z + xv.y*w1.z + xv.z*w2.z + xv.w*w3.z;
                acc[r][3] += xv.x*w0.w + xv.y*w1.w + xv.z*w2.w + xv.w*w3.w;
            }
        }
#pragma unroll
        for (int r = 0; r < 7; ++r)
            *(float4*)(&s_qkv[r0+r][col]) = make_float4(acc[r][0],acc[r][1],acc[r][2],acc[r][3]);
    }
    __syncthreads();
    if (t < 147) {
        const int g = t / 49, qi = t - g * 49, pi = qi / 7, qq = qi - pi * 7;
        float qreg[32];
#pragma unroll
        for (int d = 0; d < 32; d += 4) {
            float4 v = *(const float4*)(&s_qkv[qi][g*32 + d]);
            qreg[d]=v.x*SCALE; qreg[d+1]=v.y*SCALE; qreg[d+2]=v.z*SCALE; qreg[d+3]=v.w*SCALE;
        }
        float sim[49]; float m = -1e30f;
        for (int j = 0; j < 49; ++j) {
            float a = 0.f;
            const float* kr = &s_qkv[j][96 + g*32];
#pragma unroll
            for (int d = 0; d < 32; d += 4) {
                float4 kv = *(const float4*)(kr + d);
                a += qreg[d]*kv.x + qreg[d+1]*kv.y + qreg[d+2]*kv.z + qreg[d+3]*kv.w;
            }
            int pj = j / 7, qj = j % 7;
            a += s_rel[g*169 + (pi-pj+6)*13 + (qq-qj+6)];
            sim[j] = a; m = fmaxf(m, a);
        }
        float s = 0.f;
        for (int j = 0; j < 49; ++j) { float e = __expf(sim[j]-m); sim[j]=e; s+=e; }
        float inv = 1.f/s;
        float o[32];
#pragma unroll
        for (int d = 0; d < 32; ++d) o[d] = 0.f;
        for (int j = 0; j < 49; ++j) {
            float p = sim[j];
            const float* vr = &s_qkv[j][192 + g*32];
#pragma unroll
            for (int d = 0; d < 32; d += 4) {
                float4 vv = *(const float4*)(vr + d);
                o[d] += p*vv.x; o[d+1] += p*vv.y; o[d+2] += p*vv.z; o[d+3] += p*vv.w;
            }
        }
#pragma unroll
        for (int d = 0; d < 32; d += 4)
            *(float4*)(&s_x[qi][g*32 + d]) = make_float4(o[d]*inv, o[d+1]*inv, o[d+2]*inv, o[d+3]*inv);
    }
    __syncthreads();
    for (int u = t; u < 336; u += 256) {
        int cg = u % 48, rg = u / 48, col = cg * 2, r0 = rg * 7;
        float b0 = b_out[col], b1 = b_out[col+1];
        float acc[7][2];
#pragma unroll
        for (int r = 0; r < 7; ++r) { acc[r][0]=b0; acc[r][1]=b1; }
        for (int k = 0; k < 96; k += 4) {
            float2 w0 = *(const float2*)(w_out + (size_t)(k+0)*96 + col);
            float2 w1 = *(const float2*)(w_out + (size_t)(k+1)*96 + col);
            float2 w2 = *(const float2*)(w_out + (size_t)(k+2)*96 + col);
            float2 w3 = *(const float2*)(w_out + (size_t)(k+3)*96 + col);
#pragma unroll
            for (int r = 0; r < 7; ++r) {
                float4 xv = *(const float4*)(&s_x[r0+r][k]);
                acc[r][0] += xv.x*w0.x + xv.y*w1.x + xv.z*w2.x + xv.w*w3.x;
                acc[r][1] += xv.x*w0.y + xv.y*w1.y + xv.z*w2.y + xv.w*w3.y;
            }
        }
#pragma unroll
        for (int r = 0; r < 7; ++r)
            *(float2*)(out + (size_t)(((b*56 + rg*8 + hh)*56) + r*8 + ww)*96 + col) =
                make_float2(acc[r][0], acc[r][1]);
    }
}

extern "C" void kernel_launch(void* const* d_in, const int* in_sizes, int n_in,
                              void* d_out, int out_size, void* d_ws, size_t ws_size,
                              hipStream_t stream) {
    const float* x       = (const float*)d_in[0];
    const float* w_qkv   = (const float*)d_in[1];
    const float* b_qkv   = (const float*)d_in[2];
    const float* rel_pos = (const float*)d_in[3];
    const float* w_out   = (const float*)d_in[4];
    const float* b_out   = (const float*)d_in[5];
    float* out = (float*)d_out;

    const size_t WQT_BYTES = (size_t)288 * 96 * 2;   // 55,296
    const size_t WOT_BYTES = (size_t)96 * 96 * 2;    // 18,432

    if (ws_size >= WQT_BYTES + WOT_BYTES) {
        unsigned short* wqT = (unsigned short*)d_ws;
        unsigned short* woT = (unsigned short*)((char*)d_ws + WQT_BYTES);
        hipLaunchKernelGGL(k_prep,  dim3(144),  dim3(256), 0, stream, w_qkv, w_out, wqT, woT);
        hipLaunchKernelGGL(k_fused, dim3(4096), dim3(256), 0, stream,
                           x, wqT, b_qkv, rel_pos, woT, b_out, out);
    } else {
        hipLaunchKernelGGL(winattn_fp32, dim3(4096), dim3(256), 0, stream,
                           x, w_qkv, b_qkv, rel_pos, w_out, b_out, out);
    }
}